// Round 5
// baseline (4890.899 us; speedup 1.0000x reference)
//
#include <hip/hip_runtime.h>

#define KK 27
#define EPSV 1e-5f

typedef __attribute__((ext_vector_type(8))) short bf16x8;
typedef __attribute__((ext_vector_type(4))) float f32x4;
typedef __attribute__((ext_vector_type(4))) unsigned int u32x4;

static __device__ __forceinline__ unsigned short f2bf(float f) {
    unsigned u = __float_as_uint(f);
    u = u + 0x7fffu + ((u >> 16) & 1u);
    return (unsigned short)(u >> 16);
}
static __device__ __forceinline__ float bflo(unsigned u) { return __uint_as_float(u << 16); }
static __device__ __forceinline__ float bfhi(unsigned u) { return __uint_as_float(u & 0xffff0000u); }

// --- K0: transpose+convert W1[m][k][n] (fp32) -> WT[m][n][k] (bf16) ---
__global__ void k0_wt(const float* __restrict__ W1, unsigned short* __restrict__ WT) {
    int m = blockIdx.x >> 7, n = blockIdx.x & 127, k = threadIdx.x;
    WT[((m * 128 + n) * 128) + k] = f2bf(W1[(m * 128 + k) * 128 + n]);
}

// --- KA: y_m = x @ W1[m] for m in [m0,m1); Yall[row][(m-m0)*128 + c] bf16 (row stride ystride)
__launch_bounds__(256)
__global__ void kA_gemm(const float* __restrict__ x, const unsigned short* __restrict__ WT,
                        unsigned short* __restrict__ Yall, float* __restrict__ ysum,
                        float* __restrict__ ysq, int N, int m0, int m1, int ystride) {
    __shared__ unsigned short As[64 * 136];   // [row][k], pad 8
    __shared__ unsigned short Bs[128 * 136];  // [n][k], pad 8; reused as Ys tile per m
    const int t = threadIdx.x;
    const int i0 = blockIdx.x * 64;

#pragma unroll
    for (int it = 0; it < 8; ++it) {
        int flat = it * 256 + t;
        int r = flat >> 5, c4 = (flat & 31) * 4;
        float4 v = make_float4(0.f, 0.f, 0.f, 0.f);
        if (i0 + r < N) v = *(const float4*)(x + (size_t)(i0 + r) * 128 + c4);
        ushort4 bb;
        bb.x = f2bf(v.x); bb.y = f2bf(v.y); bb.z = f2bf(v.z); bb.w = f2bf(v.w);
        *(ushort4*)(As + r * 136 + c4) = bb;
    }

    const int w = t >> 6, lane = t & 63;
    const int wr = w >> 1, wc = w & 1;
    const int r16 = lane & 15, q = lane >> 4;

    for (int m = m0; m < m1; ++m) {
        __syncthreads();
        const uint4* Wp = (const uint4*)(WT + (size_t)m * 128 * 128);
#pragma unroll
        for (int it = 0; it < 8; ++it) {
            int flat = it * 256 + t;
            int n = flat >> 4, kc = flat & 15;
            uint4 v = Wp[n * 16 + kc];
            *(uint4*)(Bs + n * 136 + kc * 8) = v;
        }
        __syncthreads();

        f32x4 acc[2][4];
#pragma unroll
        for (int a = 0; a < 2; ++a)
#pragma unroll
            for (int b = 0; b < 4; ++b) { acc[a][b][0] = 0.f; acc[a][b][1] = 0.f; acc[a][b][2] = 0.f; acc[a][b][3] = 0.f; }

#pragma unroll
        for (int ks = 0; ks < 4; ++ks) {
            int ko = ks * 32 + q * 8;
            bf16x8 af[2], bfr[4];
#pragma unroll
            for (int ri = 0; ri < 2; ++ri)
                af[ri] = *(const bf16x8*)(As + (wr * 32 + ri * 16 + r16) * 136 + ko);
#pragma unroll
            for (int ci = 0; ci < 4; ++ci)
                bfr[ci] = *(const bf16x8*)(Bs + (wc * 64 + ci * 16 + r16) * 136 + ko);
#pragma unroll
            for (int ri = 0; ri < 2; ++ri)
#pragma unroll
                for (int ci = 0; ci < 4; ++ci)
                    acc[ri][ci] = __builtin_amdgcn_mfma_f32_16x16x32_bf16(af[ri], bfr[ci], acc[ri][ci], 0, 0, 0);
        }

#pragma unroll
        for (int ci = 0; ci < 4; ++ci) {
            float s = 0.f, s2 = 0.f;
#pragma unroll
            for (int ri = 0; ri < 2; ++ri) {
#pragma unroll
                for (int r = 0; r < 4; ++r) {
                    int row = i0 + wr * 32 + ri * 16 + q * 4 + r;
                    float vv = acc[ri][ci][r];
                    if (row < N) { s += vv; s2 += vv * vv; }
                }
            }
            s  += __shfl_xor(s, 16);  s  += __shfl_xor(s, 32);
            s2 += __shfl_xor(s2, 16); s2 += __shfl_xor(s2, 32);
            if (lane < 16) {
                int col = wc * 64 + ci * 16 + r16;
                atomicAdd(ysum + m * 128 + col, s);
                atomicAdd(ysq  + m * 128 + col, s2);
            }
        }

        __syncthreads();
        unsigned short* Ys = Bs;
#pragma unroll
        for (int ci = 0; ci < 4; ++ci) {
            int col = wc * 64 + ci * 16 + r16;
#pragma unroll
            for (int ri = 0; ri < 2; ++ri) {
#pragma unroll
                for (int r = 0; r < 4; ++r) {
                    int rl = wr * 32 + ri * 16 + q * 4 + r;
                    Ys[rl * 136 + col] = f2bf(acc[ri][ci][r]);
                }
            }
        }
        __syncthreads();
        const int cb = (m - m0) * 128;
#pragma unroll
        for (int it = 0; it < 4; ++it) {
            int chunk = it * 256 + t;
            int row = chunk >> 4, c8 = (chunk & 15) * 8;
            if (i0 + row < N) {
                u32x4 v = *(const u32x4*)(Ys + row * 136 + c8);
                __builtin_nontemporal_store(v, (u32x4*)(Yall + (size_t)(i0 + row) * ystride + cb + c8));
            }
        }
    }
}

// --- K2: finalize BN1 coefficients (blockDim = 128*nm) ---
__global__ void k2_coef(const float* __restrict__ ysum, const float* __restrict__ ysq,
                        const float* __restrict__ g1, const float* __restrict__ b1,
                        float* __restrict__ a1, float* __restrict__ c1, int N, int m0) {
    int c = threadIdx.x & 127;
    int m = m0 + (threadIdx.x >> 7);
    float mean = ysum[m * 128 + c] / (float)N;
    float var  = ysq[m * 128 + c] / (float)N - mean * mean;
    float a = g1[m * 128 + c] * rsqrtf(var + EPSV);
    a1[m * 128 + c] = a;
    c1[m * 128 + c] = b1[m * 128 + c] - mean * a;
}

// --- K4_ALL: single-pass merged gather over all 4 branches (m-inner):
//     P[i] = sum_m sum_k relu(y_m[nbr[i,k]]*a_m + c_m) * wk[m,k,:]   (write-only P)
//     + column sums/sqsums of P. Yall interleaved [N][512] bf16.
__launch_bounds__(256, 3)
__global__ void k4_all(const unsigned short* __restrict__ Yall, const int* __restrict__ nbr,
                       const float* __restrict__ wkg, const float* __restrict__ a1,
                       const float* __restrict__ c1, float* __restrict__ P,
                       float* __restrict__ osum, float* __restrict__ osq, int N) {
    __shared__ unsigned short wkL[4 * KK * 128];   // bf16 [m][k][c], 27648 B
    __shared__ float ssum[128], ssq[128];
    const int t = threadIdx.x;
    for (int idx = t; idx < 4 * KK * 128; idx += 256) wkL[idx] = f2bf(wkg[idx]);
    if (t < 128) { ssum[t] = 0.f; ssq[t] = 0.f; }

    const int lane = t & 63, w = t >> 6;
    const int q = lane >> 4, c16 = lane & 15;
    const int slot = w * 4 + q;               // 0..15

    // all 4 branches' BN coefficients for this lane's 8 channels
    float Ar[4][8], Cr[4][8];
#pragma unroll
    for (int m = 0; m < 4; ++m) {
        const float4 A0 = *(const float4*)(a1 + m * 128 + c16 * 8);
        const float4 A1 = *(const float4*)(a1 + m * 128 + c16 * 8 + 4);
        const float4 C0 = *(const float4*)(c1 + m * 128 + c16 * 8);
        const float4 C1 = *(const float4*)(c1 + m * 128 + c16 * 8 + 4);
        Ar[m][0]=A0.x; Ar[m][1]=A0.y; Ar[m][2]=A0.z; Ar[m][3]=A0.w;
        Ar[m][4]=A1.x; Ar[m][5]=A1.y; Ar[m][6]=A1.z; Ar[m][7]=A1.w;
        Cr[m][0]=C0.x; Cr[m][1]=C0.y; Cr[m][2]=C0.z; Cr[m][3]=C0.w;
        Cr[m][4]=C1.x; Cr[m][5]=C1.y; Cr[m][6]=C1.z; Cr[m][7]=C1.w;
    }
    __syncthreads();

    float os[8], oq[8];
#pragma unroll
    for (int e = 0; e < 8; ++e) { os[e] = 0.f; oq[e] = 0.f; }

    const int sweep = gridDim.x * 16;
    for (int base = blockIdx.x * 16; base < N; base += sweep) {
        const int vox = base + slot;
        const bool alive = vox < N;
        const size_t nb = (size_t)(alive ? vox : 0) * KK;
        float acc[8];
#pragma unroll
        for (int e = 0; e < 8; ++e) acc[e] = 0.f;

#pragma unroll
        for (int k = 0; k < KK; ++k) {
            const int j = nbr[nb + k];                       // quad-broadcast
            const unsigned short* row = Yall + ((size_t)j << 9) + c16 * 8;
#pragma unroll
            for (int m = 0; m < 4; ++m) {
                const uint4 hv = *(const uint4*)(row + m * 128);
                const uint4 wv = *(const uint4*)(wkL + ((m * KK + k) << 7) + c16 * 8);
                float h0 = fmaxf(0.f, bflo(hv.x) * Ar[m][0] + Cr[m][0]);
                float h1 = fmaxf(0.f, bfhi(hv.x) * Ar[m][1] + Cr[m][1]);
                float h2 = fmaxf(0.f, bflo(hv.y) * Ar[m][2] + Cr[m][2]);
                float h3 = fmaxf(0.f, bfhi(hv.y) * Ar[m][3] + Cr[m][3]);
                float h4 = fmaxf(0.f, bflo(hv.z) * Ar[m][4] + Cr[m][4]);
                float h5 = fmaxf(0.f, bfhi(hv.z) * Ar[m][5] + Cr[m][5]);
                float h6 = fmaxf(0.f, bflo(hv.w) * Ar[m][6] + Cr[m][6]);
                float h7 = fmaxf(0.f, bfhi(hv.w) * Ar[m][7] + Cr[m][7]);
                acc[0] += h0 * bflo(wv.x); acc[1] += h1 * bfhi(wv.x);
                acc[2] += h2 * bflo(wv.y); acc[3] += h3 * bfhi(wv.y);
                acc[4] += h4 * bflo(wv.z); acc[5] += h5 * bfhi(wv.z);
                acc[6] += h6 * bflo(wv.w); acc[7] += h7 * bfhi(wv.w);
            }
        }

        if (alive) {
            f32x4 v0 = {acc[0], acc[1], acc[2], acc[3]};
            f32x4 v1 = {acc[4], acc[5], acc[6], acc[7]};
            float* p = P + (size_t)vox * 128 + c16 * 8;
            __builtin_nontemporal_store(v0, (f32x4*)p);
            __builtin_nontemporal_store(v1, (f32x4*)(p + 4));
#pragma unroll
            for (int e = 0; e < 8; ++e) { os[e] += acc[e]; oq[e] += acc[e] * acc[e]; }
        }
    }

#pragma unroll
    for (int e = 0; e < 8; ++e) {
        os[e] += __shfl_xor(os[e], 16); os[e] += __shfl_xor(os[e], 32);
        oq[e] += __shfl_xor(oq[e], 16); oq[e] += __shfl_xor(oq[e], 32);
    }
    if (lane < 16) {
#pragma unroll
        for (int e = 0; e < 8; ++e) {
            atomicAdd(ssum + c16 * 8 + e, os[e]);
            atomicAdd(ssq  + c16 * 8 + e, oq[e]);
        }
    }
    __syncthreads();
    if (t < 128) {
        atomicAdd(osum + t, ssum[t]);
        atomicAdd(osq  + t, ssq[t]);
    }
}

// --- K4 fallback (per-branch, compact Y) ---
template <int MODE>
__launch_bounds__(256)
__global__ void k4_gather(const unsigned short* __restrict__ Ym, int ystride,
                          const int* __restrict__ nbr,
                          const float* __restrict__ wkm, const float* __restrict__ a1m,
                          const float* __restrict__ c1m, float* __restrict__ P,
                          float* __restrict__ osum, float* __restrict__ osq, int N) {
    __shared__ float wkL[KK * 132];
    __shared__ float ssum[128], ssq[128];
    const int t = threadIdx.x;
    for (int idx = t; idx < KK * 128; idx += 256) {
        int k = idx >> 7, c = idx & 127;
        wkL[k * 132 + c] = wkm[k * 128 + c];
    }
    if (MODE == 2) { if (t < 128) { ssum[t] = 0.f; ssq[t] = 0.f; } }

    const int w = t >> 6, lane = t & 63;
    const int q = lane >> 4, c16 = lane & 15;
    const int slot = w * 4 + q;
    const int vox = blockIdx.x * 16 + slot;
    const bool alive = vox < N;

    float aR[8], cR[8];
    {
        const float4 A0 = *(const float4*)(a1m + c16 * 8);
        const float4 A1 = *(const float4*)(a1m + c16 * 8 + 4);
        const float4 C0 = *(const float4*)(c1m + c16 * 8);
        const float4 C1 = *(const float4*)(c1m + c16 * 8 + 4);
        aR[0]=A0.x; aR[1]=A0.y; aR[2]=A0.z; aR[3]=A0.w;
        aR[4]=A1.x; aR[5]=A1.y; aR[6]=A1.z; aR[7]=A1.w;
        cR[0]=C0.x; cR[1]=C0.y; cR[2]=C0.z; cR[3]=C0.w;
        cR[4]=C1.x; cR[5]=C1.y; cR[6]=C1.z; cR[7]=C1.w;
    }
    __syncthreads();

    const long long base = alive ? (long long)vox * KK : 0;
    float acc[8];
#pragma unroll
    for (int e = 0; e < 8; ++e) acc[e] = 0.f;

#pragma unroll
    for (int k = 0; k < KK; ++k) {
        int j = nbr[base + k];
        const uint4 hv = *(const uint4*)(Ym + (size_t)j * ystride + c16 * 8);
        const float4 wa = *(const float4*)(wkL + k * 132 + c16 * 8);
        const float4 wb = *(const float4*)(wkL + k * 132 + c16 * 8 + 4);
        float h0 = fmaxf(0.f, bflo(hv.x) * aR[0] + cR[0]);
        float h1 = fmaxf(0.f, bfhi(hv.x) * aR[1] + cR[1]);
        float h2 = fmaxf(0.f, bflo(hv.y) * aR[2] + cR[2]);
        float h3 = fmaxf(0.f, bfhi(hv.y) * aR[3] + cR[3]);
        float h4 = fmaxf(0.f, bflo(hv.z) * aR[4] + cR[4]);
        float h5 = fmaxf(0.f, bfhi(hv.z) * aR[5] + cR[5]);
        float h6 = fmaxf(0.f, bflo(hv.w) * aR[6] + cR[6]);
        float h7 = fmaxf(0.f, bfhi(hv.w) * aR[7] + cR[7]);
        acc[0] += h0 * wa.x; acc[1] += h1 * wa.y;
        acc[2] += h2 * wa.z; acc[3] += h3 * wa.w;
        acc[4] += h4 * wb.x; acc[5] += h5 * wb.y;
        acc[6] += h6 * wb.z; acc[7] += h7 * wb.w;
    }

    float os[8], oq[8];
    if (alive) {
        float* p = P + (size_t)vox * 128 + c16 * 8;
        if (MODE == 0) {
            float4 v0 = {acc[0], acc[1], acc[2], acc[3]};
            float4 v1 = {acc[4], acc[5], acc[6], acc[7]};
            *(float4*)p = v0;
            *(float4*)(p + 4) = v1;
        } else {
            float4 o0 = *(const float4*)p, o1 = *(const float4*)(p + 4);
            o0.x += acc[0]; o0.y += acc[1]; o0.z += acc[2]; o0.w += acc[3];
            o1.x += acc[4]; o1.y += acc[5]; o1.z += acc[6]; o1.w += acc[7];
            *(float4*)p = o0;
            *(float4*)(p + 4) = o1;
            if (MODE == 2) {
                os[0] = o0.x; oq[0] = o0.x * o0.x;
                os[1] = o0.y; oq[1] = o0.y * o0.y;
                os[2] = o0.z; oq[2] = o0.z * o0.z;
                os[3] = o0.w; oq[3] = o0.w * o0.w;
                os[4] = o1.x; oq[4] = o1.x * o1.x;
                os[5] = o1.y; oq[5] = o1.y * o1.y;
                os[6] = o1.z; oq[6] = o1.z * o1.z;
                os[7] = o1.w; oq[7] = o1.w * o1.w;
            }
        }
    }
    if (MODE == 2) {
        if (!alive) {
#pragma unroll
            for (int e = 0; e < 8; ++e) { os[e] = 0.f; oq[e] = 0.f; }
        }
#pragma unroll
        for (int e = 0; e < 8; ++e) {
            os[e] += __shfl_xor(os[e], 16); os[e] += __shfl_xor(os[e], 32);
            oq[e] += __shfl_xor(oq[e], 16); oq[e] += __shfl_xor(oq[e], 32);
        }
        if (lane < 16) {
#pragma unroll
            for (int e = 0; e < 8; ++e) {
                atomicAdd(ssum + c16 * 8 + e, os[e]);
                atomicAdd(ssq  + c16 * 8 + e, oq[e]);
            }
        }
        __syncthreads();
        if (t < 128) {
            atomicAdd(osum + t, ssum[t]);
            atomicAdd(osq  + t, ssq[t]);
        }
    }
}

// --- K5: finalize output BN coefficients ---
__global__ void k5_coef(const float* __restrict__ osum, const float* __restrict__ osq,
                        const float* __restrict__ g, const float* __restrict__ b,
                        float* __restrict__ ao, float* __restrict__ co, int N) {
    int c = threadIdx.x;
    float mean = osum[c] / (float)N;
    float var  = osq[c] / (float)N - mean * mean;
    float a = g[c] * rsqrtf(var + EPSV);
    ao[c] = a;
    co[c] = b[c] - mean * a;
}

// --- K6: out = relu(relu(P*a + c) + x), in-place on d_out ---
__launch_bounds__(256)
__global__ void k6_final(float* __restrict__ P, const float* __restrict__ x,
                         const float* __restrict__ ao, const float* __restrict__ co, int N) {
    long long t4 = ((long long)blockIdx.x * 256 + threadIdx.x) * 4;
    if (t4 >= (long long)N * 128) return;
    int c4 = (int)(t4 & 127);
    float4 p  = *(const float4*)(P + t4);
    float4 xv = *(const float4*)(x + t4);
    float4 a  = *(const float4*)(ao + c4);
    float4 c  = *(const float4*)(co + c4);
    float4 o;
    o.x = fmaxf(0.f, fmaxf(0.f, p.x * a.x + c.x) + xv.x);
    o.y = fmaxf(0.f, fmaxf(0.f, p.y * a.y + c.y) + xv.y);
    o.z = fmaxf(0.f, fmaxf(0.f, p.z * a.z + c.z) + xv.z);
    o.w = fmaxf(0.f, fmaxf(0.f, p.w * a.w + c.w) + xv.w);
    *(float4*)(P + t4) = o;
}

extern "C" void kernel_launch(void* const* d_in, const int* in_sizes, int n_in,
                              void* d_out, int out_size, void* d_ws, size_t ws_size,
                              hipStream_t stream) {
    const float* x     = (const float*)d_in[0];
    const int*   nbr   = (const int*)d_in[1];
    const float* W1    = (const float*)d_in[2];
    const float* g1    = (const float*)d_in[3];
    const float* b1    = (const float*)d_in[4];
    const float* wk    = (const float*)d_in[5];
    const float* g_out = (const float*)d_in[6];
    const float* b_out = (const float*)d_in[7];
    const int N = in_sizes[0] / 128;

    float* P = (float*)d_out;
    char* ws = (char*)d_ws;
    float* ysum = (float*)ws;          // [512]
    float* ysq  = ysum + 512;          // [512]
    float* osum = ysq + 512;           // [128]
    float* osq  = osum + 128;          // [128]
    float* a1   = osq + 128;           // [512]
    float* c1   = a1 + 512;            // [512]
    float* ao   = c1 + 512;            // [128]
    float* co   = ao + 128;            // [128]
    unsigned short* WT = (unsigned short*)(ws + 16384);            // 4*128*128 bf16
    unsigned short* Y  = (unsigned short*)(ws + 16384 + 131072);   // Y buffer

    const bool fused = ws_size >= (size_t)16384 + 131072 + (size_t)N * 512 * 2;

    hipMemsetAsync(d_ws, 0, 5120, stream);
    k0_wt<<<512, 128, 0, stream>>>(W1, WT);

    const int gA = (N + 63) / 64;
    const int g4 = (N + 15) / 16;

    if (fused) {
        kA_gemm<<<gA, 256, 0, stream>>>(x, WT, Y, ysum, ysq, N, 0, 4, 512);
        k2_coef<<<1, 512, 0, stream>>>(ysum, ysq, g1, b1, a1, c1, N, 0);
        k4_all<<<768, 256, 0, stream>>>(Y, nbr, wk, a1, c1, P, osum, osq, N);
    } else {
        for (int m = 0; m < 4; ++m) {
            kA_gemm<<<gA, 256, 0, stream>>>(x, WT, Y, ysum, ysq, N, m, m + 1, 128);
            k2_coef<<<1, 128, 0, stream>>>(ysum, ysq, g1, b1, a1, c1, N, m);
            if (m == 0)
                k4_gather<0><<<g4, 256, 0, stream>>>(Y, 128, nbr, wk + m * KK * 128,
                                                     a1 + m * 128, c1 + m * 128, P, osum, osq, N);
            else if (m == 3)
                k4_gather<2><<<g4, 256, 0, stream>>>(Y, 128, nbr, wk + m * KK * 128,
                                                     a1 + m * 128, c1 + m * 128, P, osum, osq, N);
            else
                k4_gather<1><<<g4, 256, 0, stream>>>(Y, 128, nbr, wk + m * KK * 128,
                                                     a1 + m * 128, c1 + m * 128, P, osum, osq, N);
        }
    }
    k5_coef<<<1, 128, 0, stream>>>(osum, osq, g_out, b_out, ao, co, N);
    const int g6 = (int)(((long long)N * 128 / 4 + 255) / 256);
    k6_final<<<g6, 256, 0, stream>>>(P, x, ao, co, N);
}

// Round 6
// 629.958 us; speedup vs baseline: 7.7639x; 7.7639x over previous
//
#include <hip/hip_runtime.h>

#define KK 27
#define EPSV 1e-5f

typedef __attribute__((ext_vector_type(8))) short bf16x8;
typedef __attribute__((ext_vector_type(4))) float f32x4;
typedef __attribute__((ext_vector_type(4))) unsigned int u32x4;

static __device__ __forceinline__ unsigned short f2bf(float f) {
    unsigned u = __float_as_uint(f);
    u = u + 0x7fffu + ((u >> 16) & 1u);
    return (unsigned short)(u >> 16);
}
static __device__ __forceinline__ float bflo(unsigned u) { return __uint_as_float(u << 16); }
static __device__ __forceinline__ float bfhi(unsigned u) { return __uint_as_float(u & 0xffff0000u); }

// --- K0: transpose+convert W1[m][k][n] (fp32) -> WT[m][n][k] (bf16) ---
__global__ void k0_wt(const float* __restrict__ W1, unsigned short* __restrict__ WT) {
    int m = blockIdx.x >> 7, n = blockIdx.x & 127, k = threadIdx.x;
    WT[((m * 128 + n) * 128) + k] = f2bf(W1[(m * 128 + k) * 128 + n]);
}

// --- KA: y_m = x @ W1[m] for m in [m0,m1); Yall[row][(m-m0)*128 + c] bf16 (row stride ystride)
__launch_bounds__(256)
__global__ void kA_gemm(const float* __restrict__ x, const unsigned short* __restrict__ WT,
                        unsigned short* __restrict__ Yall, float* __restrict__ ysum,
                        float* __restrict__ ysq, int N, int m0, int m1, int ystride) {
    __shared__ unsigned short As[64 * 136];   // [row][k], pad 8
    __shared__ unsigned short Bs[128 * 136];  // [n][k], pad 8; reused as Ys tile per m
    const int t = threadIdx.x;
    const int i0 = blockIdx.x * 64;

#pragma unroll
    for (int it = 0; it < 8; ++it) {
        int flat = it * 256 + t;
        int r = flat >> 5, c4 = (flat & 31) * 4;
        float4 v = make_float4(0.f, 0.f, 0.f, 0.f);
        if (i0 + r < N) v = *(const float4*)(x + (size_t)(i0 + r) * 128 + c4);
        ushort4 bb;
        bb.x = f2bf(v.x); bb.y = f2bf(v.y); bb.z = f2bf(v.z); bb.w = f2bf(v.w);
        *(ushort4*)(As + r * 136 + c4) = bb;
    }

    const int w = t >> 6, lane = t & 63;
    const int wr = w >> 1, wc = w & 1;
    const int r16 = lane & 15, q = lane >> 4;

    for (int m = m0; m < m1; ++m) {
        __syncthreads();
        const uint4* Wp = (const uint4*)(WT + (size_t)m * 128 * 128);
#pragma unroll
        for (int it = 0; it < 8; ++it) {
            int flat = it * 256 + t;
            int n = flat >> 4, kc = flat & 15;
            uint4 v = Wp[n * 16 + kc];
            *(uint4*)(Bs + n * 136 + kc * 8) = v;
        }
        __syncthreads();

        f32x4 acc[2][4];
#pragma unroll
        for (int a = 0; a < 2; ++a)
#pragma unroll
            for (int b = 0; b < 4; ++b) { acc[a][b][0] = 0.f; acc[a][b][1] = 0.f; acc[a][b][2] = 0.f; acc[a][b][3] = 0.f; }

#pragma unroll
        for (int ks = 0; ks < 4; ++ks) {
            int ko = ks * 32 + q * 8;
            bf16x8 af[2], bfr[4];
#pragma unroll
            for (int ri = 0; ri < 2; ++ri)
                af[ri] = *(const bf16x8*)(As + (wr * 32 + ri * 16 + r16) * 136 + ko);
#pragma unroll
            for (int ci = 0; ci < 4; ++ci)
                bfr[ci] = *(const bf16x8*)(Bs + (wc * 64 + ci * 16 + r16) * 136 + ko);
#pragma unroll
            for (int ri = 0; ri < 2; ++ri)
#pragma unroll
                for (int ci = 0; ci < 4; ++ci)
                    acc[ri][ci] = __builtin_amdgcn_mfma_f32_16x16x32_bf16(af[ri], bfr[ci], acc[ri][ci], 0, 0, 0);
        }

#pragma unroll
        for (int ci = 0; ci < 4; ++ci) {
            float s = 0.f, s2 = 0.f;
#pragma unroll
            for (int ri = 0; ri < 2; ++ri) {
#pragma unroll
                for (int r = 0; r < 4; ++r) {
                    int row = i0 + wr * 32 + ri * 16 + q * 4 + r;
                    float vv = acc[ri][ci][r];
                    if (row < N) { s += vv; s2 += vv * vv; }
                }
            }
            s  += __shfl_xor(s, 16);  s  += __shfl_xor(s, 32);
            s2 += __shfl_xor(s2, 16); s2 += __shfl_xor(s2, 32);
            if (lane < 16) {
                int col = wc * 64 + ci * 16 + r16;
                atomicAdd(ysum + m * 128 + col, s);
                atomicAdd(ysq  + m * 128 + col, s2);
            }
        }

        __syncthreads();
        unsigned short* Ys = Bs;
#pragma unroll
        for (int ci = 0; ci < 4; ++ci) {
            int col = wc * 64 + ci * 16 + r16;
#pragma unroll
            for (int ri = 0; ri < 2; ++ri) {
#pragma unroll
                for (int r = 0; r < 4; ++r) {
                    int rl = wr * 32 + ri * 16 + q * 4 + r;
                    Ys[rl * 136 + col] = f2bf(acc[ri][ci][r]);
                }
            }
        }
        __syncthreads();
        const int cb = (m - m0) * 128;
#pragma unroll
        for (int it = 0; it < 4; ++it) {
            int chunk = it * 256 + t;
            int row = chunk >> 4, c8 = (chunk & 15) * 8;
            if (i0 + row < N) {
                u32x4 v = *(const u32x4*)(Ys + row * 136 + c8);
                __builtin_nontemporal_store(v, (u32x4*)(Yall + (size_t)(i0 + row) * ystride + cb + c8));
            }
        }
    }
}

// --- K2: finalize BN1 coefficients (blockDim = 128*nm) ---
__global__ void k2_coef(const float* __restrict__ ysum, const float* __restrict__ ysq,
                        const float* __restrict__ g1, const float* __restrict__ b1,
                        float* __restrict__ a1, float* __restrict__ c1, int N, int m0) {
    int c = threadIdx.x & 127;
    int m = m0 + (threadIdx.x >> 7);
    float mean = ysum[m * 128 + c] / (float)N;
    float var  = ysq[m * 128 + c] / (float)N - mean * mean;
    float a = g1[m * 128 + c] * rsqrtf(var + EPSV);
    a1[m * 128 + c] = a;
    c1[m * 128 + c] = b1[m * 128 + c] - mean * a;
}

// --- K4_ALL v2: merged gather, one voxel per wave, full 1KB row per load.
//     lane: m = lane>>4, c16 = lane&15. Cross-m sum via shfl_xor(16,32).
//     nbr scalarized via readfirstlane. No spills: unroll 3.
__launch_bounds__(256)
__global__ void k4_all(const unsigned short* __restrict__ Yall, const int* __restrict__ nbr,
                       const float* __restrict__ wkg, const float* __restrict__ a1,
                       const float* __restrict__ c1, float* __restrict__ P,
                       float* __restrict__ osum, float* __restrict__ osq, int N) {
    __shared__ unsigned short wkL[4 * KK * 136];   // bf16 [m*27+k][c] pad 8
    __shared__ float ssum[128], ssq[128];
    const int t = threadIdx.x;
    for (int idx = t; idx < 4 * KK * 128; idx += 256) {
        int c = idx & 127, km = idx >> 7;          // km = m*27+k (c inner)
        wkL[km * 136 + c] = f2bf(wkg[idx]);
    }
    if (t < 128) { ssum[t] = 0.f; ssq[t] = 0.f; }

    const int lane = t & 63;
    const int m = lane >> 4, c16 = lane & 15;

    // BN coefficients for THIS lane's branch m, channels c16*8..+8
    float Ar[8], Cr[8];
    {
        const float4 A0 = *(const float4*)(a1 + m * 128 + c16 * 8);
        const float4 A1 = *(const float4*)(a1 + m * 128 + c16 * 8 + 4);
        const float4 C0 = *(const float4*)(c1 + m * 128 + c16 * 8);
        const float4 C1 = *(const float4*)(c1 + m * 128 + c16 * 8 + 4);
        Ar[0]=A0.x; Ar[1]=A0.y; Ar[2]=A0.z; Ar[3]=A0.w;
        Ar[4]=A1.x; Ar[5]=A1.y; Ar[6]=A1.z; Ar[7]=A1.w;
        Cr[0]=C0.x; Cr[1]=C0.y; Cr[2]=C0.z; Cr[3]=C0.w;
        Cr[4]=C1.x; Cr[5]=C1.y; Cr[6]=C1.z; Cr[7]=C1.w;
    }
    __syncthreads();

    float os[8], oq[8];
#pragma unroll
    for (int e = 0; e < 8; ++e) { os[e] = 0.f; oq[e] = 0.f; }

    const int wid = blockIdx.x * 4 + (t >> 6);
    const int nw  = gridDim.x * 4;
    for (int vox = wid; vox < N; vox += nw) {
        const int sv = __builtin_amdgcn_readfirstlane(vox);
        const int* np = nbr + (size_t)sv * KK;     // wave-uniform -> s_load
        float acc[8];
#pragma unroll
        for (int e = 0; e < 8; ++e) acc[e] = 0.f;

#pragma unroll 3
        for (int k = 0; k < KK; ++k) {
            const int j = np[k];
            // whole wave loads the full 1KB interleaved row: lane*16B
            const uint4 hv = *(const uint4*)(Yall + ((size_t)j << 9) + lane * 8);
            const uint4 wv = *(const uint4*)(wkL + (m * KK + k) * 136 + c16 * 8);
            float h0 = fmaxf(0.f, bflo(hv.x) * Ar[0] + Cr[0]);
            float h1 = fmaxf(0.f, bfhi(hv.x) * Ar[1] + Cr[1]);
            float h2 = fmaxf(0.f, bflo(hv.y) * Ar[2] + Cr[2]);
            float h3 = fmaxf(0.f, bfhi(hv.y) * Ar[3] + Cr[3]);
            float h4 = fmaxf(0.f, bflo(hv.z) * Ar[4] + Cr[4]);
            float h5 = fmaxf(0.f, bfhi(hv.z) * Ar[5] + Cr[5]);
            float h6 = fmaxf(0.f, bflo(hv.w) * Ar[6] + Cr[6]);
            float h7 = fmaxf(0.f, bfhi(hv.w) * Ar[7] + Cr[7]);
            acc[0] += h0 * bflo(wv.x); acc[1] += h1 * bfhi(wv.x);
            acc[2] += h2 * bflo(wv.y); acc[3] += h3 * bfhi(wv.y);
            acc[4] += h4 * bflo(wv.z); acc[5] += h5 * bfhi(wv.z);
            acc[6] += h6 * bflo(wv.w); acc[7] += h7 * bfhi(wv.w);
        }

        // sum over the 4 branches (quads): lanes {l, l^16, l^32, l^48}
#pragma unroll
        for (int e = 0; e < 8; ++e) {
            acc[e] += __shfl_xor(acc[e], 16);
            acc[e] += __shfl_xor(acc[e], 32);
        }

        if (lane < 16) {     // quad 0 stores the 512B row + accumulates stats
            f32x4 v0 = {acc[0], acc[1], acc[2], acc[3]};
            f32x4 v1 = {acc[4], acc[5], acc[6], acc[7]};
            float* p = P + (size_t)vox * 128 + c16 * 8;
            __builtin_nontemporal_store(v0, (f32x4*)p);
            __builtin_nontemporal_store(v1, (f32x4*)(p + 4));
#pragma unroll
            for (int e = 0; e < 8; ++e) { os[e] += acc[e]; oq[e] += acc[e] * acc[e]; }
        }
    }

    if (lane < 16) {
#pragma unroll
        for (int e = 0; e < 8; ++e) {
            atomicAdd(ssum + c16 * 8 + e, os[e]);
            atomicAdd(ssq  + c16 * 8 + e, oq[e]);
        }
    }
    __syncthreads();
    if (t < 128) {
        atomicAdd(osum + t, ssum[t]);
        atomicAdd(osq  + t, ssq[t]);
    }
}

// --- K4 fallback (per-branch, compact Y) ---
template <int MODE>
__launch_bounds__(256)
__global__ void k4_gather(const unsigned short* __restrict__ Ym, int ystride,
                          const int* __restrict__ nbr,
                          const float* __restrict__ wkm, const float* __restrict__ a1m,
                          const float* __restrict__ c1m, float* __restrict__ P,
                          float* __restrict__ osum, float* __restrict__ osq, int N) {
    __shared__ float wkL[KK * 132];
    __shared__ float ssum[128], ssq[128];
    const int t = threadIdx.x;
    for (int idx = t; idx < KK * 128; idx += 256) {
        int k = idx >> 7, c = idx & 127;
        wkL[k * 132 + c] = wkm[k * 128 + c];
    }
    if (MODE == 2) { if (t < 128) { ssum[t] = 0.f; ssq[t] = 0.f; } }

    const int w = t >> 6, lane = t & 63;
    const int q = lane >> 4, c16 = lane & 15;
    const int slot = w * 4 + q;
    const int vox = blockIdx.x * 16 + slot;
    const bool alive = vox < N;

    float aR[8], cR[8];
    {
        const float4 A0 = *(const float4*)(a1m + c16 * 8);
        const float4 A1 = *(const float4*)(a1m + c16 * 8 + 4);
        const float4 C0 = *(const float4*)(c1m + c16 * 8);
        const float4 C1 = *(const float4*)(c1m + c16 * 8 + 4);
        aR[0]=A0.x; aR[1]=A0.y; aR[2]=A0.z; aR[3]=A0.w;
        aR[4]=A1.x; aR[5]=A1.y; aR[6]=A1.z; aR[7]=A1.w;
        cR[0]=C0.x; cR[1]=C0.y; cR[2]=C0.z; cR[3]=C0.w;
        cR[4]=C1.x; cR[5]=C1.y; cR[6]=C1.z; cR[7]=C1.w;
    }
    __syncthreads();

    const long long base = alive ? (long long)vox * KK : 0;
    float acc[8];
#pragma unroll
    for (int e = 0; e < 8; ++e) acc[e] = 0.f;

#pragma unroll 3
    for (int k = 0; k < KK; ++k) {
        int j = nbr[base + k];
        const uint4 hv = *(const uint4*)(Ym + (size_t)j * ystride + c16 * 8);
        const float4 wa = *(const float4*)(wkL + k * 132 + c16 * 8);
        const float4 wb = *(const float4*)(wkL + k * 132 + c16 * 8 + 4);
        float h0 = fmaxf(0.f, bflo(hv.x) * aR[0] + cR[0]);
        float h1 = fmaxf(0.f, bfhi(hv.x) * aR[1] + cR[1]);
        float h2 = fmaxf(0.f, bflo(hv.y) * aR[2] + cR[2]);
        float h3 = fmaxf(0.f, bfhi(hv.y) * aR[3] + cR[3]);
        float h4 = fmaxf(0.f, bflo(hv.z) * aR[4] + cR[4]);
        float h5 = fmaxf(0.f, bfhi(hv.z) * aR[5] + cR[5]);
        float h6 = fmaxf(0.f, bflo(hv.w) * aR[6] + cR[6]);
        float h7 = fmaxf(0.f, bfhi(hv.w) * aR[7] + cR[7]);
        acc[0] += h0 * wa.x; acc[1] += h1 * wa.y;
        acc[2] += h2 * wa.z; acc[3] += h3 * wa.w;
        acc[4] += h4 * wb.x; acc[5] += h5 * wb.y;
        acc[6] += h6 * wb.z; acc[7] += h7 * wb.w;
    }

    float os[8], oq[8];
    if (alive) {
        float* p = P + (size_t)vox * 128 + c16 * 8;
        if (MODE == 0) {
            float4 v0 = {acc[0], acc[1], acc[2], acc[3]};
            float4 v1 = {acc[4], acc[5], acc[6], acc[7]};
            *(float4*)p = v0;
            *(float4*)(p + 4) = v1;
        } else {
            float4 o0 = *(const float4*)p, o1 = *(const float4*)(p + 4);
            o0.x += acc[0]; o0.y += acc[1]; o0.z += acc[2]; o0.w += acc[3];
            o1.x += acc[4]; o1.y += acc[5]; o1.z += acc[6]; o1.w += acc[7];
            *(float4*)p = o0;
            *(float4*)(p + 4) = o1;
            if (MODE == 2) {
                os[0] = o0.x; oq[0] = o0.x * o0.x;
                os[1] = o0.y; oq[1] = o0.y * o0.y;
                os[2] = o0.z; oq[2] = o0.z * o0.z;
                os[3] = o0.w; oq[3] = o0.w * o0.w;
                os[4] = o1.x; oq[4] = o1.x * o1.x;
                os[5] = o1.y; oq[5] = o1.y * o1.y;
                os[6] = o1.z; oq[6] = o1.z * o1.z;
                os[7] = o1.w; oq[7] = o1.w * o1.w;
            }
        }
    }
    if (MODE == 2) {
        if (!alive) {
#pragma unroll
            for (int e = 0; e < 8; ++e) { os[e] = 0.f; oq[e] = 0.f; }
        }
#pragma unroll
        for (int e = 0; e < 8; ++e) {
            os[e] += __shfl_xor(os[e], 16); os[e] += __shfl_xor(os[e], 32);
            oq[e] += __shfl_xor(oq[e], 16); oq[e] += __shfl_xor(oq[e], 32);
        }
        if (lane < 16) {
#pragma unroll
            for (int e = 0; e < 8; ++e) {
                atomicAdd(ssum + c16 * 8 + e, os[e]);
                atomicAdd(ssq  + c16 * 8 + e, oq[e]);
            }
        }
        __syncthreads();
        if (t < 128) {
            atomicAdd(osum + t, ssum[t]);
            atomicAdd(osq  + t, ssq[t]);
        }
    }
}

// --- K5: finalize output BN coefficients ---
__global__ void k5_coef(const float* __restrict__ osum, const float* __restrict__ osq,
                        const float* __restrict__ g, const float* __restrict__ b,
                        float* __restrict__ ao, float* __restrict__ co, int N) {
    int c = threadIdx.x;
    float mean = osum[c] / (float)N;
    float var  = osq[c] / (float)N - mean * mean;
    float a = g[c] * rsqrtf(var + EPSV);
    ao[c] = a;
    co[c] = b[c] - mean * a;
}

// --- K6: out = relu(relu(P*a + c) + x), in-place on d_out ---
__launch_bounds__(256)
__global__ void k6_final(float* __restrict__ P, const float* __restrict__ x,
                         const float* __restrict__ ao, const float* __restrict__ co, int N) {
    long long t4 = ((long long)blockIdx.x * 256 + threadIdx.x) * 4;
    if (t4 >= (long long)N * 128) return;
    int c4 = (int)(t4 & 127);
    float4 p  = *(const float4*)(P + t4);
    float4 xv = *(const float4*)(x + t4);
    float4 a  = *(const float4*)(ao + c4);
    float4 c  = *(const float4*)(co + c4);
    float4 o;
    o.x = fmaxf(0.f, fmaxf(0.f, p.x * a.x + c.x) + xv.x);
    o.y = fmaxf(0.f, fmaxf(0.f, p.y * a.y + c.y) + xv.y);
    o.z = fmaxf(0.f, fmaxf(0.f, p.z * a.z + c.z) + xv.z);
    o.w = fmaxf(0.f, fmaxf(0.f, p.w * a.w + c.w) + xv.w);
    *(float4*)(P + t4) = o;
}

extern "C" void kernel_launch(void* const* d_in, const int* in_sizes, int n_in,
                              void* d_out, int out_size, void* d_ws, size_t ws_size,
                              hipStream_t stream) {
    const float* x     = (const float*)d_in[0];
    const int*   nbr   = (const int*)d_in[1];
    const float* W1    = (const float*)d_in[2];
    const float* g1    = (const float*)d_in[3];
    const float* b1    = (const float*)d_in[4];
    const float* wk    = (const float*)d_in[5];
    const float* g_out = (const float*)d_in[6];
    const float* b_out = (const float*)d_in[7];
    const int N = in_sizes[0] / 128;

    float* P = (float*)d_out;
    char* ws = (char*)d_ws;
    float* ysum = (float*)ws;          // [512]
    float* ysq  = ysum + 512;          // [512]
    float* osum = ysq + 512;           // [128]
    float* osq  = osum + 128;          // [128]
    float* a1   = osq + 128;           // [512]
    float* c1   = a1 + 512;            // [512]
    float* ao   = c1 + 512;            // [128]
    float* co   = ao + 128;            // [128]
    unsigned short* WT = (unsigned short*)(ws + 16384);            // 4*128*128 bf16
    unsigned short* Y  = (unsigned short*)(ws + 16384 + 131072);   // Y buffer

    const bool fused = ws_size >= (size_t)16384 + 131072 + (size_t)N * 512 * 2;

    hipMemsetAsync(d_ws, 0, 5120, stream);
    k0_wt<<<512, 128, 0, stream>>>(W1, WT);

    const int gA = (N + 63) / 64;
    const int g4 = (N + 15) / 16;

    if (fused) {
        kA_gemm<<<gA, 256, 0, stream>>>(x, WT, Y, ysum, ysq, N, 0, 4, 512);
        k2_coef<<<1, 512, 0, stream>>>(ysum, ysq, g1, b1, a1, c1, N, 0);
        k4_all<<<2048, 256, 0, stream>>>(Y, nbr, wk, a1, c1, P, osum, osq, N);
    } else {
        for (int m = 0; m < 4; ++m) {
            kA_gemm<<<gA, 256, 0, stream>>>(x, WT, Y, ysum, ysq, N, m, m + 1, 128);
            k2_coef<<<1, 128, 0, stream>>>(ysum, ysq, g1, b1, a1, c1, N, m);
            if (m == 0)
                k4_gather<0><<<g4, 256, 0, stream>>>(Y, 128, nbr, wk + m * KK * 128,
                                                     a1 + m * 128, c1 + m * 128, P, osum, osq, N);
            else if (m == 3)
                k4_gather<2><<<g4, 256, 0, stream>>>(Y, 128, nbr, wk + m * KK * 128,
                                                     a1 + m * 128, c1 + m * 128, P, osum, osq, N);
            else
                k4_gather<1><<<g4, 256, 0, stream>>>(Y, 128, nbr, wk + m * KK * 128,
                                                     a1 + m * 128, c1 + m * 128, P, osum, osq, N);
        }
    }
    k5_coef<<<1, 128, 0, stream>>>(osum, osq, g_out, b_out, ao, co, N);
    const int g6 = (int)(((long long)N * 128 / 4 + 255) / 256);
    k6_final<<<g6, 256, 0, stream>>>(P, x, ao, co, N);
}